// Round 1
// 7199.436 us; speedup vs baseline: 1.1538x; 1.1538x over previous
//
#include <hip/hip_runtime.h>
#include <math.h>

// GPT forward w/ learned token pruning.
// Mask path numerics: imp ~1e-3 vs th ~1e-4 with ~0.3% rel spacing near the
// crossing -> plain bf16 GEMMs would flip mask bits. Layer GEMMs use
// split-bf16 3-term MFMA (err ~2^-17 rel, fp32-like). LM head (no mask
// dependency) uses plain bf16 MFMA. PV/softmax stay fp32; QK^T is 3-term
// split-bf16 (err ~1e-5 rel, 300x margin vs mask spacing).
//
// This revision hoists ALL fp32->bf16 split conversion OUT of the GEMM hot
// loops (old version re-converted every operand tile in-loop -> VALUBusy 31%
// vs MfmaUtil 11.6%). Weights are transpose-split once per launch into N x K
// bf16 hi/lo; activations are emitted pre-split by their producers
// (layernorm / GEMM epilogues). The GEMM hot loop is the m97 structure:
// 128x128 tile, BK=32, linear [128][32] LDS tiles via global_load_lds(16B),
// ds_read_b128 fragments, MFMA-only inner loop.
// Fallback: if ws_size < ~600 MB, run the previous (verified) path.

#define LNUM 12
#define HNUM 12
#define CDIM 768
#define VDIM 50304
#define TDIM 1024
#define BDIM 2
#define NROWS 2048   // B*T
#define LDSK 40      // old-path LDS row stride (bf16 elems)

typedef unsigned short u16;
typedef __attribute__((ext_vector_type(8))) short short8;
typedef __attribute__((ext_vector_type(4))) float floatx4;
typedef __attribute__((ext_vector_type(4))) unsigned short ushort4v;
typedef __attribute__((ext_vector_type(8))) unsigned short ushort8v;

__device__ __forceinline__ unsigned short f2bf_rne(float f) {
  unsigned u = __float_as_uint(f);
  u += 0x7fff + ((u >> 16) & 1);
  return (unsigned short)(u >> 16);
}
__device__ __forceinline__ float bf2f(unsigned short h) {
  return __uint_as_float(((unsigned)h) << 16);
}

// async global->LDS, 16 bytes per lane. lds ptr must be wave-uniform;
// HW writes lane l at lds + l*16.
__device__ __forceinline__ void gload16(const void* g, void* l) {
  __builtin_amdgcn_global_load_lds(
      (const __attribute__((address_space(1))) unsigned int*)g,
      (__attribute__((address_space(3))) unsigned int*)l, 16, 0, 0);
}

// ---------- block reduction (256 threads) ----------
__device__ __forceinline__ float bred(float v, int op) {  // op: 0 sum, 1 max
  __shared__ float red[256];
  const int tid = threadIdx.x;
  red[tid] = v;
  __syncthreads();
#pragma unroll
  for (int s = 128; s > 0; s >>= 1) {
    if (tid < s) {
      float o = red[tid + s];
      red[tid] = op ? fmaxf(red[tid], o) : (red[tid] + o);
    }
    __syncthreads();
  }
  float r = red[0];
  __syncthreads();
  return r;
}

// ---------- embedding + am init ----------
__global__ void k_embed(const int* __restrict__ idx, const float* __restrict__ wte,
                        const float* __restrict__ wpe, float* __restrict__ x,
                        float* __restrict__ am) {
  const int row = blockIdx.x;
  const int t = row & (TDIM - 1);
  const long tok = idx[row];
  const float* src = wte + tok * CDIM;
  const float* pp = wpe + (long)t * CDIM;
  float* dst = x + (long)row * CDIM;
  for (int c = threadIdx.x; c < CDIM; c += 256) dst[c] = src[c] + pp[c];
  if (threadIdx.x == 0) am[row] = 1.0f;
}

// ---------- layernorm (fp32 out, fallback path) ----------
__global__ void k_layernorm(const float* __restrict__ in, const float* __restrict__ w,
                            const float* __restrict__ b, float* __restrict__ out) {
  const long row = blockIdx.x;
  const int tid = threadIdx.x;
  const float* xr = in + row * CDIM;
  float v0 = xr[tid], v1 = xr[tid + 256], v2 = xr[tid + 512];
  float mean = bred(v0 + v1 + v2, 0) * (1.0f / CDIM);
  float d0 = v0 - mean, d1 = v1 - mean, d2 = v2 - mean;
  float var = bred(d0 * d0 + d1 * d1 + d2 * d2, 0) * (1.0f / CDIM);
  float inv = 1.0f / sqrtf(var + 1e-5f);
  float* orow = out + row * CDIM;
  orow[tid]       = d0 * inv * w[tid]       + b[tid];
  orow[tid + 256] = d1 * inv * w[tid + 256] + b[tid + 256];
  orow[tid + 512] = d2 * inv * w[tid + 512] + b[tid + 512];
}

// ---------- layernorm, split bf16 hi/lo out (new path) ----------
__global__ void k_layernorm_sp(const float* __restrict__ in, const float* __restrict__ w,
                               const float* __restrict__ b, u16* __restrict__ ohi,
                               u16* __restrict__ olo) {
  const long row = blockIdx.x;
  const int tid = threadIdx.x;
  const float* xr = in + row * CDIM;
  float v0 = xr[tid], v1 = xr[tid + 256], v2 = xr[tid + 512];
  float mean = bred(v0 + v1 + v2, 0) * (1.0f / CDIM);
  float d0 = v0 - mean, d1 = v1 - mean, d2 = v2 - mean;
  float var = bred(d0 * d0 + d1 * d1 + d2 * d2, 0) * (1.0f / CDIM);
  float inv = 1.0f / sqrtf(var + 1e-5f);
  float o0 = d0 * inv * w[tid]       + b[tid];
  float o1 = d1 * inv * w[tid + 256] + b[tid + 256];
  float o2 = d2 * inv * w[tid + 512] + b[tid + 512];
  u16* hr = ohi + row * CDIM;
  u16* lr = olo + row * CDIM;
  u16 h0 = f2bf_rne(o0), h1 = f2bf_rne(o1), h2 = f2bf_rne(o2);
  hr[tid] = h0;       lr[tid] = f2bf_rne(o0 - bf2f(h0));
  hr[tid + 256] = h1; lr[tid + 256] = f2bf_rne(o1 - bf2f(h1));
  hr[tid + 512] = h2; lr[tid + 512] = f2bf_rne(o2 - bf2f(h2));
}

// ---------- weight transpose + split: W[K][N] fp32 -> Wt_hi/lo [N][K] bf16 ----------
__global__ void k_wsplit(const float* __restrict__ W, u16* __restrict__ Whi,
                         u16* __restrict__ Wlo, int K, int N, long wstride, long ostride) {
  W += blockIdx.z * wstride;
  Whi += blockIdx.z * ostride;
  Wlo += blockIdx.z * ostride;
  const int n0 = blockIdx.x << 6, k0 = blockIdx.y << 6;
  __shared__ float t[64][65];
  const int tid = threadIdx.x;
  const int cr = tid >> 4;          // 0..15
  const int cc = (tid & 15) << 2;   // 0..60 step 4
#pragma unroll
  for (int it = 0; it < 4; ++it) {
    const int r = cr + it * 16;
    float4 v = *(const float4*)(W + (long)(k0 + r) * N + n0 + cc);
    t[r][cc] = v.x; t[r][cc + 1] = v.y; t[r][cc + 2] = v.z; t[r][cc + 3] = v.w;
  }
  __syncthreads();
#pragma unroll
  for (int it = 0; it < 4; ++it) {
    const int n = cr + it * 16;
    ushort4v hv, lv;
#pragma unroll
    for (int j = 0; j < 4; ++j) {
      float f = t[cc + j][n];
      u16 hh = f2bf_rne(f);
      hv[j] = hh;
      lv[j] = f2bf_rne(f - bf2f(hh));
    }
    *(ushort4v*)&Whi[(long)(n0 + n) * K + k0 + cc] = hv;
    *(ushort4v*)&Wlo[(long)(n0 + n) * K + k0 + cc] = lv;
  }
}

// ---------- fp32 -> bf16 hi conversion (wte for LM head) ----------
__global__ void k_cvt_hi(const float* __restrict__ A, u16* __restrict__ O, long n) {
  long i = ((long)blockIdx.x * 256 + threadIdx.x) * 8;
  if (i >= n) return;
  float4 a = *(const float4*)(A + i);
  float4 b = *(const float4*)(A + i + 4);
  ushort8v o;
  o[0] = f2bf_rne(a.x); o[1] = f2bf_rne(a.y); o[2] = f2bf_rne(a.z); o[3] = f2bf_rne(a.w);
  o[4] = f2bf_rne(b.x); o[5] = f2bf_rne(b.y); o[6] = f2bf_rne(b.z); o[7] = f2bf_rne(b.w);
  *(ushort8v*)&O[i] = o;
}

// ---------- fp32 GEMM (QK^T fallback, PV). OSPLIT=1: write bf16 hi/lo outs ----------
template <int BT, int ACT, int OSPLIT>
__global__ __launch_bounds__(256) void k_gemm(
    const float* __restrict__ A, const float* __restrict__ B,
    const float* __restrict__ bias, float* __restrict__ C,
    u16* __restrict__ Ohi, u16* __restrict__ Olo,
    int K, int lda, int ldb, int ldc,
    long sAb, long sAh, long sBb, long sBh, long sCb, long sCh,
    int Hb, float alpha, int beta) {
  const int bid = blockIdx.z;
  const int bb = bid / Hb, hh = bid - bb * Hb;
  A += bb * sAb + hh * sAh;
  B += bb * sBb + hh * sBh;
  C += bb * sCb + hh * sCh;
  if (OSPLIT) { Ohi += bb * sCb + hh * sCh; Olo += bb * sCb + hh * sCh; }
  const int m0 = blockIdx.y << 6, n0 = blockIdx.x << 6;
  __shared__ float As[16][68];
  __shared__ float Bs[16][68];
  const int tid = threadIdx.x;
  const int r0 = (tid >> 4) << 2;
  const int c0 = (tid & 15) << 2;
  const int lr = tid >> 2;
  const int lk = (tid & 3) << 2;
  const int bk = tid >> 4;
  const int bn = (tid & 15) << 2;
  float acc[4][4] = {{0.f, 0.f, 0.f, 0.f}, {0.f, 0.f, 0.f, 0.f},
                     {0.f, 0.f, 0.f, 0.f}, {0.f, 0.f, 0.f, 0.f}};
  for (int k0 = 0; k0 < K; k0 += 16) {
    float4 av = *(const float4*)(A + (long)(m0 + lr) * lda + (k0 + lk));
    As[lk][lr] = av.x; As[lk + 1][lr] = av.y; As[lk + 2][lr] = av.z; As[lk + 3][lr] = av.w;
    if (BT) {
      float4 bv = *(const float4*)(B + (long)(n0 + lr) * ldb + (k0 + lk));
      Bs[lk][lr] = bv.x; Bs[lk + 1][lr] = bv.y; Bs[lk + 2][lr] = bv.z; Bs[lk + 3][lr] = bv.w;
    } else {
      *(float4*)&Bs[bk][bn] = *(const float4*)(B + (long)(k0 + bk) * ldb + (n0 + bn));
    }
    __syncthreads();
#pragma unroll
    for (int kk = 0; kk < 16; ++kk) {
      float4 a = *(const float4*)&As[kk][r0];
      float4 bv = *(const float4*)&Bs[kk][c0];
      acc[0][0] += a.x * bv.x; acc[0][1] += a.x * bv.y; acc[0][2] += a.x * bv.z; acc[0][3] += a.x * bv.w;
      acc[1][0] += a.y * bv.x; acc[1][1] += a.y * bv.y; acc[1][2] += a.y * bv.z; acc[1][3] += a.y * bv.w;
      acc[2][0] += a.z * bv.x; acc[2][1] += a.z * bv.y; acc[2][2] += a.z * bv.z; acc[2][3] += a.z * bv.w;
      acc[3][0] += a.w * bv.x; acc[3][1] += a.w * bv.y; acc[3][2] += a.w * bv.z; acc[3][3] += a.w * bv.w;
    }
    __syncthreads();
  }
  float4 bs4 = make_float4(0.f, 0.f, 0.f, 0.f);
  if (bias) bs4 = *(const float4*)(bias + n0 + c0);
#pragma unroll
  for (int i = 0; i < 4; ++i) {
    float* cp = C + (long)(m0 + r0 + i) * ldc + (n0 + c0);
    float4 prev = make_float4(0.f, 0.f, 0.f, 0.f);
    if (beta) prev = *(const float4*)cp;
    float4 o;
    o.x = prev.x + alpha * acc[i][0] + bs4.x;
    o.y = prev.y + alpha * acc[i][1] + bs4.y;
    o.z = prev.z + alpha * acc[i][2] + bs4.z;
    o.w = prev.w + alpha * acc[i][3] + bs4.w;
    if (ACT == 1) {
      o.x = 0.5f * o.x * (1.0f + erff(o.x * 0.70710678118654752f));
      o.y = 0.5f * o.y * (1.0f + erff(o.y * 0.70710678118654752f));
      o.z = 0.5f * o.z * (1.0f + erff(o.z * 0.70710678118654752f));
      o.w = 0.5f * o.w * (1.0f + erff(o.w * 0.70710678118654752f));
    }
    if (OSPLIT) {
      ushort4v hv, lv;
      hv[0] = f2bf_rne(o.x); lv[0] = f2bf_rne(o.x - bf2f(hv[0]));
      hv[1] = f2bf_rne(o.y); lv[1] = f2bf_rne(o.y - bf2f(hv[1]));
      hv[2] = f2bf_rne(o.z); lv[2] = f2bf_rne(o.z - bf2f(hv[2]));
      hv[3] = f2bf_rne(o.w); lv[3] = f2bf_rne(o.w - bf2f(hv[3]));
      *(ushort4v*)(Ohi + (long)(m0 + r0 + i) * ldc + (n0 + c0)) = hv;
      *(ushort4v*)(Olo + (long)(m0 + r0 + i) * ldc + (n0 + c0)) = lv;
    } else {
      *(float4*)cp = o;
    }
  }
}

// ---------- NEW: pre-split bf16 MFMA GEMM (m97 staging structure) ----------
// A_hi/lo: [M][K] bf16 row-major (lda). B_hi/lo: [N][K] bf16 row-major (ldb)
// (i.e. B-transposed storage). C fp32 [M][N] (ldc). TERMS=3: 3-term split
// product hi*hi + hi*lo + lo*hi. OUTMODE: 0 fp32 C; 1 bf16 hi/lo only;
// 2 both. Batched via blockIdx.z = bb*Hb + hh with element strides.
// 128x128 tile, BK=32, 4 waves (2x2), 4x4 frags of 16x16x32 per wave.
// LDS tiles are linear [128][32] filled by global_load_lds width 16.
template <int TERMS, int ACT, int OUTMODE, int GS>
__global__ __launch_bounds__(256) void k_gemm_bt(
    const u16* __restrict__ Ahi, const u16* __restrict__ Alo,
    const u16* __restrict__ Bhi, const u16* __restrict__ Blo,
    const float* __restrict__ bias, float* __restrict__ C,
    u16* __restrict__ Ohi, u16* __restrict__ Olo,
    int K, int lda, int ldb, int ldc,
    long sAb, long sAh, long sBb, long sBh, long sCb, long sCh,
    int Hb, float alpha, int beta) {
  const int bz = blockIdx.z;
  const int bb = bz / Hb, hh = bz - bb * Hb;
  Ahi += bb * sAb + hh * sAh;
  Bhi += bb * sBb + hh * sBh;
  if (TERMS > 1) {
    Alo += bb * sAb + hh * sAh;
    Blo += bb * sBb + hh * sBh;
  }
  if (OUTMODE != 1) C += bb * sCb + hh * sCh;
  if (OUTMODE >= 1) { Ohi += bb * sCb + hh * sCh; Olo += bb * sCb + hh * sCh; }
  const int m0 = (GS ? blockIdx.x : blockIdx.y) << 7;
  const int n0 = (GS ? blockIdx.y : blockIdx.x) << 7;
  __shared__ u16 sm[(TERMS > 1 ? 4 : 2) * 4096];
  u16* sAhi = sm;
  u16* sAlo = sm + 4096;                              // used only TERMS>1
  u16* sBhi = sm + (TERMS > 1 ? 2 : 1) * 4096;
  u16* sBlo = sBhi + 4096;                            // used only TERMS>1
  const int tid = threadIdx.x;
  const int lane = tid & 63, wave = tid >> 6;
  const int wm = (wave & 1) << 6, wn = (wave >> 1) << 6;
  const int fr = lane & 15, fk = (lane >> 4) << 3;
  // staging: wave w fills chunks 2w,2w+1 (16 rows x 32 cols each);
  // lane l covers row chunkrow + (l>>2), cols (l&3)*8 .. +7  (16 B).
  const int sr = lane >> 2;
  const int sc = (lane & 3) << 3;
  const long arow = (long)(m0 + wave * 32 + sr);
  const long brow = (long)(n0 + wave * 32 + sr);
  const int lbase = wave * 1024;   // u16 index of this wave's first chunk

  floatx4 acc[4][4];
#pragma unroll
  for (int i = 0; i < 4; ++i)
#pragma unroll
    for (int j = 0; j < 4; ++j) acc[i][j] = (floatx4)(0.0f);

  for (int k0 = 0; k0 < K; k0 += 32) {
    {
      const u16* ga = Ahi + arow * lda + k0 + sc;
      const u16* gb = Bhi + brow * ldb + k0 + sc;
      gload16(ga, &sAhi[lbase]);
      gload16(ga + (long)16 * lda, &sAhi[lbase + 512]);
      gload16(gb, &sBhi[lbase]);
      gload16(gb + (long)16 * ldb, &sBhi[lbase + 512]);
      if (TERMS > 1) {
        const u16* ga2 = Alo + arow * lda + k0 + sc;
        const u16* gb2 = Blo + brow * ldb + k0 + sc;
        gload16(ga2, &sAlo[lbase]);
        gload16(ga2 + (long)16 * lda, &sAlo[lbase + 512]);
        gload16(gb2, &sBlo[lbase]);
        gload16(gb2 + (long)16 * ldb, &sBlo[lbase + 512]);
      }
    }
    __syncthreads();
    short8 ah[4], bh[4], al[4], bl[4];
#pragma unroll
    for (int i = 0; i < 4; ++i) {
      ah[i] = *(const short8*)&sAhi[(wm + i * 16 + fr) * 32 + fk];
      bh[i] = *(const short8*)&sBhi[(wn + i * 16 + fr) * 32 + fk];
      if (TERMS > 1) {
        al[i] = *(const short8*)&sAlo[(wm + i * 16 + fr) * 32 + fk];
        bl[i] = *(const short8*)&sBlo[(wn + i * 16 + fr) * 32 + fk];
      }
    }
#pragma unroll
    for (int i = 0; i < 4; ++i)
#pragma unroll
      for (int j = 0; j < 4; ++j) {
        acc[i][j] = __builtin_amdgcn_mfma_f32_16x16x32_bf16(ah[i], bh[j], acc[i][j], 0, 0, 0);
        if (TERMS > 1) {
          acc[i][j] = __builtin_amdgcn_mfma_f32_16x16x32_bf16(ah[i], bl[j], acc[i][j], 0, 0, 0);
          acc[i][j] = __builtin_amdgcn_mfma_f32_16x16x32_bf16(al[i], bh[j], acc[i][j], 0, 0, 0);
        }
      }
    __syncthreads();
  }
  // epilogue: C/D map col=lane&15, row=(lane>>4)*4+reg
  const int er = (lane >> 4) << 2, ec = lane & 15;
#pragma unroll
  for (int j = 0; j < 4; ++j) {
    const int col = n0 + wn + j * 16 + ec;
    const float bsv = bias ? bias[col] : 0.0f;
#pragma unroll
    for (int i = 0; i < 4; ++i) {
      const long rbase = (long)(m0 + wm + i * 16 + er);
#pragma unroll
      for (int r = 0; r < 4; ++r) {
        const long off = (rbase + r) * ldc + col;
        float o = alpha * acc[i][j][r] + bsv;
        if (beta) o += C[off];
        if (ACT == 1) o = 0.5f * o * (1.0f + erff(o * 0.70710678118654752f));
        if (OUTMODE != 1) C[off] = o;
        if (OUTMODE >= 1) {
          u16 hv = f2bf_rne(o);
          Ohi[off] = hv;
          Olo[off] = f2bf_rne(o - bf2f(hv));
        }
      }
    }
  }
}

// ---------- OLD: MFMA GEMM with in-loop conversion (fallback path) ----------
template <int BT, int TERMS, int ACT, int GS>
__global__ __launch_bounds__(256) void k_gemm_mfma(
    const float* __restrict__ A, const float* __restrict__ B,
    const float* __restrict__ bias, float* __restrict__ C,
    int K, int lda, int ldb, int ldc, int beta) {
  const int m0 = (GS ? blockIdx.x : blockIdx.y) << 7;
  const int n0 = (GS ? blockIdx.y : blockIdx.x) << 7;
  __shared__ unsigned short sm[(TERMS > 1 ? 4 : 2) * 128 * LDSK];
  unsigned short* As_hi = sm;
  unsigned short* As_lo = (TERMS > 1) ? (sm + 128 * LDSK) : sm;
  unsigned short* Bs_hi = sm + (TERMS > 1 ? 2 : 1) * 128 * LDSK;
  unsigned short* Bs_lo = (TERMS > 1) ? (Bs_hi + 128 * LDSK) : Bs_hi;
  const int tid = threadIdx.x;
  const int lane = tid & 63, wave = tid >> 6;
  const int wm = (wave & 1) << 6, wn = (wave >> 1) << 6;
  const int fr = lane & 15;
  const int fk = (lane >> 4) << 3;
  const int ar = tid >> 1, ak = (tid & 1) << 4;
  const int bn = tid & 31, bk = (tid >> 5) << 2;

  floatx4 acc[4][4];
#pragma unroll
  for (int i = 0; i < 4; ++i)
#pragma unroll
    for (int j = 0; j < 4; ++j) acc[i][j] = (floatx4)(0.0f);

  for (int k0 = 0; k0 < K; k0 += 32) {
    {
      const float* ap = A + (long)(m0 + ar) * lda + (k0 + ak);
      float4 f0 = *(const float4*)(ap);
      float4 f1 = *(const float4*)(ap + 4);
      float4 f2 = *(const float4*)(ap + 8);
      float4 f3 = *(const float4*)(ap + 12);
      float va[16] = {f0.x, f0.y, f0.z, f0.w, f1.x, f1.y, f1.z, f1.w,
                      f2.x, f2.y, f2.z, f2.w, f3.x, f3.y, f3.z, f3.w};
      ushort8v h0, h1, l0, l1;
#pragma unroll
      for (int i = 0; i < 8; ++i) {
        unsigned short hA = f2bf_rne(va[i]);
        unsigned short hB = f2bf_rne(va[8 + i]);
        h0[i] = hA; h1[i] = hB;
        if (TERMS > 1) {
          l0[i] = f2bf_rne(va[i] - bf2f(hA));
          l1[i] = f2bf_rne(va[8 + i] - bf2f(hB));
        }
      }
      *(ushort8v*)&As_hi[ar * LDSK + ak]     = h0;
      *(ushort8v*)&As_hi[ar * LDSK + ak + 8] = h1;
      if (TERMS > 1) {
        *(ushort8v*)&As_lo[ar * LDSK + ak]     = l0;
        *(ushort8v*)&As_lo[ar * LDSK + ak + 8] = l1;
      }
    }
    if (BT) {
      const float* bp = B + (long)(n0 + ar) * ldb + (k0 + ak);
      float4 f0 = *(const float4*)(bp);
      float4 f1 = *(const float4*)(bp + 4);
      float4 f2 = *(const float4*)(bp + 8);
      float4 f3 = *(const float4*)(bp + 12);
      float vb[16] = {f0.x, f0.y, f0.z, f0.w, f1.x, f1.y, f1.z, f1.w,
                      f2.x, f2.y, f2.z, f2.w, f3.x, f3.y, f3.z, f3.w};
      ushort8v h0, h1, l0, l1;
#pragma unroll
      for (int i = 0; i < 8; ++i) {
        unsigned short hA = f2bf_rne(vb[i]);
        unsigned short hB = f2bf_rne(vb[8 + i]);
        h0[i] = hA; h1[i] = hB;
        if (TERMS > 1) {
          l0[i] = f2bf_rne(vb[i] - bf2f(hA));
          l1[i] = f2bf_rne(vb[8 + i] - bf2f(hB));
        }
      }
      *(ushort8v*)&Bs_hi[ar * LDSK + ak]     = h0;
      *(ushort8v*)&Bs_hi[ar * LDSK + ak + 8] = h1;
      if (TERMS > 1) {
        *(ushort8v*)&Bs_lo[ar * LDSK + ak]     = l0;
        *(ushort8v*)&Bs_lo[ar * LDSK + ak + 8] = l1;
      }
    } else {
      float bvv[4][4];
#pragma unroll
      for (int j = 0; j < 4; ++j)
#pragma unroll
        for (int r = 0; r < 4; ++r)
          bvv[j][r] = B[(long)(k0 + bk + r) * ldb + (n0 + bn + 32 * j)];
#pragma unroll
      for (int j = 0; j < 4; ++j) {
        ushort4v hv, lv;
#pragma unroll
        for (int r = 0; r < 4; ++r) {
          unsigned short hh = f2bf_rne(bvv[j][r]);
          hv[r] = hh;
          if (TERMS > 1) lv[r] = f2bf_rne(bvv[j][r] - bf2f(hh));
        }
        *(ushort4v*)&Bs_hi[(bn + 32 * j) * LDSK + bk] = hv;
        if (TERMS > 1) *(ushort4v*)&Bs_lo[(bn + 32 * j) * LDSK + bk] = lv;
      }
    }
    __syncthreads();
    short8 a_hi[4], a_lo[4], b_hi[4], b_lo[4];
#pragma unroll
    for (int i = 0; i < 4; ++i) {
      a_hi[i] = *(const short8*)&As_hi[(wm + i * 16 + fr) * LDSK + fk];
      b_hi[i] = *(const short8*)&Bs_hi[(wn + i * 16 + fr) * LDSK + fk];
      if (TERMS > 1) {
        a_lo[i] = *(const short8*)&As_lo[(wm + i * 16 + fr) * LDSK + fk];
        b_lo[i] = *(const short8*)&Bs_lo[(wn + i * 16 + fr) * LDSK + fk];
      }
    }
#pragma unroll
    for (int i = 0; i < 4; ++i)
#pragma unroll
      for (int j = 0; j < 4; ++j) {
        acc[i][j] = __builtin_amdgcn_mfma_f32_16x16x32_bf16(a_hi[i], b_hi[j], acc[i][j], 0, 0, 0);
        if (TERMS > 1) {
          acc[i][j] = __builtin_amdgcn_mfma_f32_16x16x32_bf16(a_hi[i], b_lo[j], acc[i][j], 0, 0, 0);
          acc[i][j] = __builtin_amdgcn_mfma_f32_16x16x32_bf16(a_lo[i], b_hi[j], acc[i][j], 0, 0, 0);
        }
      }
    __syncthreads();
  }
  const int er = (lane >> 4) << 2;
  const int ec = lane & 15;
#pragma unroll
  for (int j = 0; j < 4; ++j) {
    const int col = n0 + wn + j * 16 + ec;
    const float bsv = bias ? bias[col] : 0.0f;
#pragma unroll
    for (int i = 0; i < 4; ++i) {
#pragma unroll
      for (int r = 0; r < 4; ++r) {
        float* cp = C + (long)(m0 + wm + i * 16 + er + r) * ldc + col;
        float o = acc[i][j][r] + bsv + (beta ? *cp : 0.0f);
        if (ACT == 1) o = 0.5f * o * (1.0f + erff(o * 0.70710678118654752f));
        *cp = o;
      }
    }
  }
}

// ---------- masked softmax over keys ----------
__global__ void k_softmax(float* __restrict__ att, const float* __restrict__ am) {
  const int q = blockIdx.x;
  const int bh = blockIdx.y;
  const int b = bh / HNUM;
  float* row = att + ((long)bh * TDIM + q) * TDIM;
  const float* amr = am + b * TDIM;
  const int tid = threadIdx.x;
  float lv[4];
  bool valid[4];
  float mx = -INFINITY;
#pragma unroll
  for (int i = 0; i < 4; ++i) {
    const int k = tid + (i << 8);
    const bool ok = (k <= q) && (amr[k] > 0.0f);
    valid[i] = ok;
    lv[i] = ok ? row[k] : -INFINITY;
    mx = fmaxf(mx, lv[i]);
  }
  mx = bred(mx, 1);
  float sum = 0.f;
#pragma unroll
  for (int i = 0; i < 4; ++i) {
    lv[i] = valid[i] ? expf(lv[i] - mx) : 0.0f;
    sum += lv[i];
  }
  sum = bred(sum, 0);
  const float inv = sum > 0.f ? 1.0f / sum : 0.0f;
#pragma unroll
  for (int i = 0; i < 4; ++i) row[tid + (i << 8)] = lv[i] * inv;
}

// ---------- imp[b,k] partial column sums of att ----------
__global__ void k_impsum(const float* __restrict__ att, float* __restrict__ imp) {
  const int h = blockIdx.x >> 2, qc = blockIdx.x & 3;
  const int b = blockIdx.z;
  const int k = (blockIdx.y << 8) + threadIdx.x;
  const float* base = att + (((long)(b * HNUM + h) * TDIM) + (qc << 8)) * TDIM + k;
  float s = 0.f;
#pragma unroll 4
  for (int q = 0; q < 256; ++q) s += base[(long)q * TDIM];
  atomicAdd(&imp[b * TDIM + k], s);
}

// ---------- threshold mask ----------
__global__ void k_mask(const float* __restrict__ imp, const float* __restrict__ thp,
                       float* __restrict__ am, float* __restrict__ x) {
  const int row = blockIdx.x;
  const int t = row & (TDIM - 1);
  const float impv = imp[row] * (1.0f / (HNUM * TDIM));
  float pm = (impv >= *thp) ? 1.0f : 0.0f;
  if (t >= TDIM - 64) pm = 1.0f;
  const float cm = am[row] * pm;
  float* xr = x + (long)row * CDIM;
  const int tid = threadIdx.x;
  xr[tid] *= cm;
  xr[tid + 256] *= cm;
  xr[tid + 512] *= cm;
  if (tid == 0) am[row] = cm;
}

// ---------- loss ----------
__global__ void k_lossrow(const float* __restrict__ logits, const int* __restrict__ tgt,
                          float* __restrict__ nll) {
  const int row = blockIdx.x;
  const float* lr = logits + (long)row * VDIM;
  const int tid = threadIdx.x;
  float mx = -INFINITY;
  for (int k = tid; k < VDIM; k += 256) mx = fmaxf(mx, lr[k]);
  mx = bred(mx, 1);
  float s = 0.f;
  for (int k = tid; k < VDIM; k += 256) s += expf(lr[k] - mx);
  s = bred(s, 0);
  if (tid == 0) {
    const int t = tgt[row];
    nll[row] = (t != -1) ? -(lr[t] - mx - logf(s)) : 0.0f;
  }
}

__global__ void k_lossfinal(const float* __restrict__ nll, const int* __restrict__ tgt,
                            float* __restrict__ out) {
  const int tid = threadIdx.x;
  float s = 0.f, cnt = 0.f;
  for (int r = tid; r < NROWS; r += 256) {
    s += nll[r];
    cnt += (tgt[r] != -1) ? 1.f : 0.f;
  }
  s = bred(s, 0);
  cnt = bred(cnt, 0);
  if (tid == 0) out[0] = s / cnt;
}

extern "C" void kernel_launch(void* const* d_in, const int* in_sizes, int n_in,
                              void* d_out, int out_size, void* d_ws, size_t ws_size,
                              hipStream_t stream) {
  (void)in_sizes; (void)n_in; (void)out_size;
  const int* idx      = (const int*)d_in[0];
  const int* targets  = (const int*)d_in[1];
  const float* wte    = (const float*)d_in[2];
  const float* wpe    = (const float*)d_in[3];
  const float* ln1_w  = (const float*)d_in[4];
  const float* ln1_b  = (const float*)d_in[5];
  const float* attn_w = (const float*)d_in[6];
  const float* attn_b = (const float*)d_in[7];
  const float* proj_w = (const float*)d_in[8];
  const float* proj_b = (const float*)d_in[9];
  const float* ln2_w  = (const float*)d_in[10];
  const float* ln2_b  = (const float*)d_in[11];
  const float* fc_w   = (const float*)d_in[12];
  const float* fc_b   = (const float*)d_in[13];
  const float* mlp_w  = (const float*)d_in[14];
  const float* mlp_b  = (const float*)d_in[15];
  const float* thres  = (const float*)d_in[16];
  const float* lnf_w  = (const float*)d_in[17];
  const float* lnf_b  = (const float*)d_in[18];
  float* logits = (float*)d_out;
  float* loss = logits + (long)NROWS * VDIM;

  const long F_X   = (long)NROWS * CDIM;
  const long F_QKV = (long)NROWS * 3 * CDIM;
  const long F_ATT = (long)BDIM * HNUM * TDIM * TDIM;
  const long U_H   = (long)NROWS * CDIM;
  const long U_ACT = (long)NROWS * 4 * CDIM;
  const long U_QKV = F_QKV;
  const long WA = (long)CDIM * 3 * CDIM;   // per-layer weight elem counts
  const long WP = (long)CDIM * CDIM;
  const long WF = (long)CDIM * 4 * CDIM;
  const long WM = (long)4 * CDIM * CDIM;
  const long WPL = WA + WP + WF + WM;      // 7,077,888
  const long U_W   = (long)LNUM * WPL;
  const long U_WTE = (long)VDIM * CDIM;
  const unsigned long long need =
      4ull * (F_X + F_QKV + F_ATT + 3 * NROWS) +
      2ull * (4 * U_H + 2 * U_ACT + 2 * U_QKV + 2 * U_W + U_WTE);

  // common float region
  float* x   = (float*)d_ws;
  float* qkv = x + F_X;

  if (ws_size >= need) {
    // ================= NEW PATH: pre-split bf16 operands =================
    float* att = qkv + F_QKV;
    float* am  = att + F_ATT;
    float* imp = am + NROWS;
    float* nll = imp + NROWS;
    u16* h_hi   = (u16*)(nll + NROWS);
    u16* h_lo   = h_hi + U_H;
    u16* y_hi   = h_lo + U_H;
    u16* y_lo   = y_hi + U_H;
    u16* act_hi = y_lo + U_H;
    u16* act_lo = act_hi + U_ACT;
    u16* qkv_hi = act_lo + U_ACT;
    u16* qkv_lo = qkv_hi + U_QKV;
    u16* w_hi   = qkv_lo + U_QKV;
    u16* w_lo   = w_hi + U_W;
    u16* wte_h  = w_lo + U_W;

    // --- pre-pass: weight transpose+split (K x N fp32 -> N x K bf16 hi/lo) ---
    k_wsplit<<<dim3(3 * CDIM / 64, CDIM / 64, LNUM), 256, 0, stream>>>(
        attn_w, w_hi, w_lo, CDIM, 3 * CDIM, WA, WPL);
    k_wsplit<<<dim3(CDIM / 64, CDIM / 64, LNUM), 256, 0, stream>>>(
        proj_w, w_hi + WA, w_lo + WA, CDIM, CDIM, WP, WPL);
    k_wsplit<<<dim3(4 * CDIM / 64, CDIM / 64, LNUM), 256, 0, stream>>>(
        fc_w, w_hi + WA + WP, w_lo + WA + WP, CDIM, 4 * CDIM, WF, WPL);
    k_wsplit<<<dim3(CDIM / 64, 4 * CDIM / 64, LNUM), 256, 0, stream>>>(
        mlp_w, w_hi + WA + WP + WF, w_lo + WA + WP + WF, 4 * CDIM, CDIM, WM, WPL);
    k_cvt_hi<<<(unsigned)((U_WTE / 8 + 255) / 256), 256, 0, stream>>>(wte, wte_h, U_WTE);

    k_embed<<<NROWS, 256, 0, stream>>>(idx, wte, wpe, x, am);

    for (int l = 0; l < LNUM; ++l) {
      const u16* wa_h = w_hi + (long)l * WPL;
      const u16* wa_l = w_lo + (long)l * WPL;
      const u16* wp_h = wa_h + WA;
      const u16* wp_l = wa_l + WA;
      const u16* wf_h = wp_h + WP;
      const u16* wf_l = wp_l + WP;
      const u16* wm_h = wf_h + WF;
      const u16* wm_l = wf_l + WF;

      k_layernorm_sp<<<NROWS, 256, 0, stream>>>(x, ln1_w + l * CDIM, ln1_b + l * CDIM, h_hi, h_lo);
      // qkv = h @ attn_w + b (split-bf16, pre-split operands); also emit hi/lo
      k_gemm_bt<3, 0, 2, 0><<<dim3(18, 16), 256, 0, stream>>>(
          h_hi, h_lo, wa_h, wa_l, attn_b + (long)l * 3 * CDIM, qkv, qkv_hi, qkv_lo,
          768, 768, 768, 2304, 0, 0, 0, 0, 0, 0, 1, 1.0f, 0);
      // scores = q @ k^T / 8 (batched 3-term split-bf16 MFMA, K=64)
      k_gemm_bt<3, 0, 0, 0><<<dim3(8, 8, BDIM * HNUM), 256, 0, stream>>>(
          qkv_hi, qkv_lo, qkv_hi + CDIM, qkv_lo + CDIM, nullptr, att, nullptr, nullptr,
          64, 2304, 2304, 1024,
          (long)TDIM * 3 * CDIM, 64, (long)TDIM * 3 * CDIM, 64,
          (long)HNUM * TDIM * TDIM, (long)TDIM * TDIM, HNUM, 0.125f, 0);
      k_softmax<<<dim3(TDIM, BDIM * HNUM), 256, 0, stream>>>(att, am);
      hipMemsetAsync(imp, 0, NROWS * sizeof(float), stream);
      k_impsum<<<dim3(HNUM * 4, 4, BDIM), 256, 0, stream>>>(att, imp);
      // y = att @ v (fp32), epilogue emits y hi/lo split
      k_gemm<0, 0, 1><<<dim3(1, 16, BDIM * HNUM), 256, 0, stream>>>(
          att, qkv + 2 * CDIM, nullptr, nullptr, y_hi, y_lo,
          1024, 1024, 2304, 768,
          (long)HNUM * TDIM * TDIM, (long)TDIM * TDIM, (long)TDIM * 3 * CDIM, 64,
          (long)TDIM * CDIM, 64, HNUM, 1.0f, 0);
      // x += y @ proj_w + b
      k_gemm_bt<3, 0, 0, 0><<<dim3(6, 16), 256, 0, stream>>>(
          y_hi, y_lo, wp_h, wp_l, proj_b + (long)l * CDIM, x, nullptr, nullptr,
          768, 768, 768, 768, 0, 0, 0, 0, 0, 0, 1, 1.0f, 1);
      k_mask<<<NROWS, 256, 0, stream>>>(imp, thres + l, am, x);
      k_layernorm_sp<<<NROWS, 256, 0, stream>>>(x, ln2_w + l * CDIM, ln2_b + l * CDIM, h_hi, h_lo);
      // act = gelu(h @ fc_w + b), emitted as hi/lo split only
      k_gemm_bt<3, 1, 1, 0><<<dim3(24, 16), 256, 0, stream>>>(
          h_hi, h_lo, wf_h, wf_l, fc_b + (long)l * 4 * CDIM, nullptr, act_hi, act_lo,
          768, 768, 768, 3072, 0, 0, 0, 0, 0, 0, 1, 1.0f, 0);
      // x += act @ mlp_w + b
      k_gemm_bt<3, 0, 0, 0><<<dim3(6, 16), 256, 0, stream>>>(
          act_hi, act_lo, wm_h, wm_l, mlp_b + (long)l * CDIM, x, nullptr, nullptr,
          3072, 3072, 3072, 768, 0, 0, 0, 0, 0, 0, 1, 1.0f, 1);
    }

    k_layernorm_sp<<<NROWS, 256, 0, stream>>>(x, lnf_w, lnf_b, h_hi, h_lo);
    // logits = h @ wte^T (plain bf16, pre-converted wte; grid-swapped so the
    // 16 m-tiles sharing a wte n-tile are dispatched consecutively -> L2 reuse)
    k_gemm_bt<1, 0, 0, 1><<<dim3(16, 393), 256, 0, stream>>>(
        h_hi, nullptr, wte_h, nullptr, nullptr, logits, nullptr, nullptr,
        768, 768, 768, VDIM, 0, 0, 0, 0, 0, 0, 1, 1.0f, 0);
    k_lossrow<<<NROWS, 256, 0, stream>>>(logits, targets, nll);
    k_lossfinal<<<1, 256, 0, stream>>>(nll, targets, loss);
  } else {
    // ================= FALLBACK: previous verified path =================
    float* h    = qkv;  // re-derive old layout exactly
    h    = x + F_X;
    qkv  = h + F_X;
    float* att  = qkv + F_QKV;
    float* ybuf = att + F_ATT;
    float* act  = ybuf + F_X;
    float* am   = act + (long)NROWS * 4 * CDIM;
    float* imp  = am + NROWS;
    float* nll  = imp + NROWS;

    k_embed<<<NROWS, 256, 0, stream>>>(idx, wte, wpe, x, am);
    for (int l = 0; l < LNUM; ++l) {
      k_layernorm<<<NROWS, 256, 0, stream>>>(x, ln1_w + l * CDIM, ln1_b + l * CDIM, h);
      k_gemm_mfma<0, 3, 0, 0><<<dim3(18, 16), 256, 0, stream>>>(
          h, attn_w + (long)l * CDIM * 3 * CDIM, attn_b + (long)l * 3 * CDIM, qkv,
          768, 768, 2304, 2304, 0);
      k_gemm<1, 0, 0><<<dim3(16, 16, 24), 256, 0, stream>>>(
          qkv, qkv + CDIM, nullptr, att, nullptr, nullptr,
          64, 2304, 2304, 1024,
          (long)TDIM * 3 * CDIM, 64, (long)TDIM * 3 * CDIM, 64,
          (long)HNUM * TDIM * TDIM, (long)TDIM * TDIM, HNUM, 0.125f, 0);
      k_softmax<<<dim3(TDIM, BDIM * HNUM), 256, 0, stream>>>(att, am);
      hipMemsetAsync(imp, 0, NROWS * sizeof(float), stream);
      k_impsum<<<dim3(HNUM * 4, 4, BDIM), 256, 0, stream>>>(att, imp);
      k_gemm<0, 0, 0><<<dim3(1, 16, 24), 256, 0, stream>>>(
          att, qkv + 2 * CDIM, nullptr, ybuf, nullptr, nullptr,
          1024, 1024, 2304, 768,
          (long)HNUM * TDIM * TDIM, (long)TDIM * TDIM, (long)TDIM * 3 * CDIM, 64,
          (long)TDIM * CDIM, 64, HNUM, 1.0f, 0);
      k_gemm_mfma<0, 3, 0, 0><<<dim3(6, 16), 256, 0, stream>>>(
          ybuf, proj_w + (long)l * CDIM * CDIM, proj_b + (long)l * CDIM, x,
          768, 768, 768, 768, 1);
      k_mask<<<NROWS, 256, 0, stream>>>(imp, thres + l, am, x);
      k_layernorm<<<NROWS, 256, 0, stream>>>(x, ln2_w + l * CDIM, ln2_b + l * CDIM, h);
      k_gemm_mfma<0, 3, 1, 0><<<dim3(24, 16), 256, 0, stream>>>(
          h, fc_w + (long)l * CDIM * 4 * CDIM, fc_b + (long)l * 4 * CDIM, act,
          768, 768, 3072, 3072, 0);
      k_gemm_mfma<0, 3, 0, 0><<<dim3(6, 16), 256, 0, stream>>>(
          act, mlp_w + (long)l * 4 * CDIM * CDIM, mlp_b + (long)l * CDIM, x,
          3072, 3072, 768, 768, 1);
    }
    k_layernorm<<<NROWS, 256, 0, stream>>>(x, lnf_w, lnf_b, h);
    k_gemm_mfma<1, 1, 0, 1><<<dim3(16, 393), 256, 0, stream>>>(
        h, wte, nullptr, logits, 768, 768, 768, VDIM, 0);
    k_lossrow<<<NROWS, 256, 0, stream>>>(logits, targets, nll);
    k_lossfinal<<<1, 256, 0, stream>>>(nll, targets, loss);
  }
}

// Round 2
// 6064.581 us; speedup vs baseline: 1.3697x; 1.1871x over previous
//
#include <hip/hip_runtime.h>
#include <math.h>

// GPT forward w/ learned token pruning.
// Mask path numerics: imp ~1e-3 vs th ~1e-4 with ~0.3% rel spacing near the
// crossing -> plain bf16 GEMMs would flip mask bits. Layer GEMMs use
// split-bf16 3-term MFMA (err ~2^-17 rel, fp32-like). LM head (no mask
// dependency) uses plain bf16 MFMA. PV/softmax stay fp32; QK^T is 3-term
// split-bf16 (err ~1e-5 rel, 300x margin vs mask spacing).
//
// Round-2: attack grid starvation. mlp/proj had 96 blocks on 256 CUs (1
// wave/SIMD, 60% of CUs idle); qkv 288. Split-K with fp32 atomicAdd
// epilogue gives 384-576 blocks. XCD-chunk swizzle (bijective) on all big
// GEMMs so shared B panels live in one XCD's L2 (LM-head fetch was 3x
// ideal). lossrow is now single-pass online softmax (half the logit reads).
// Fallback: if ws_size < ~600 MB, run the round-0 verified path.

#define LNUM 12
#define HNUM 12
#define CDIM 768
#define VDIM 50304
#define TDIM 1024
#define BDIM 2
#define NROWS 2048   // B*T
#define LDSK 40      // old-path LDS row stride (bf16 elems)

typedef unsigned short u16;
typedef __attribute__((ext_vector_type(8))) short short8;
typedef __attribute__((ext_vector_type(4))) float floatx4;
typedef __attribute__((ext_vector_type(4))) unsigned short ushort4v;
typedef __attribute__((ext_vector_type(8))) unsigned short ushort8v;

__device__ __forceinline__ unsigned short f2bf_rne(float f) {
  unsigned u = __float_as_uint(f);
  u += 0x7fff + ((u >> 16) & 1);
  return (unsigned short)(u >> 16);
}
__device__ __forceinline__ float bf2f(unsigned short h) {
  return __uint_as_float(((unsigned)h) << 16);
}

// async global->LDS, 16 bytes per lane. lds ptr must be wave-uniform;
// HW writes lane l at lds + l*16.
__device__ __forceinline__ void gload16(const void* g, void* l) {
  __builtin_amdgcn_global_load_lds(
      (const __attribute__((address_space(1))) unsigned int*)g,
      (__attribute__((address_space(3))) unsigned int*)l, 16, 0, 0);
}

// ---------- block reduction (256 threads) ----------
__device__ __forceinline__ float bred(float v, int op) {  // op: 0 sum, 1 max
  __shared__ float red[256];
  const int tid = threadIdx.x;
  red[tid] = v;
  __syncthreads();
#pragma unroll
  for (int s = 128; s > 0; s >>= 1) {
    if (tid < s) {
      float o = red[tid + s];
      red[tid] = op ? fmaxf(red[tid], o) : (red[tid] + o);
    }
    __syncthreads();
  }
  float r = red[0];
  __syncthreads();
  return r;
}

// ---------- embedding + am init ----------
__global__ void k_embed(const int* __restrict__ idx, const float* __restrict__ wte,
                        const float* __restrict__ wpe, float* __restrict__ x,
                        float* __restrict__ am) {
  const int row = blockIdx.x;
  const int t = row & (TDIM - 1);
  const long tok = idx[row];
  const float* src = wte + tok * CDIM;
  const float* pp = wpe + (long)t * CDIM;
  float* dst = x + (long)row * CDIM;
  for (int c = threadIdx.x; c < CDIM; c += 256) dst[c] = src[c] + pp[c];
  if (threadIdx.x == 0) am[row] = 1.0f;
}

// ---------- layernorm (fp32 out, fallback path) ----------
__global__ void k_layernorm(const float* __restrict__ in, const float* __restrict__ w,
                            const float* __restrict__ b, float* __restrict__ out) {
  const long row = blockIdx.x;
  const int tid = threadIdx.x;
  const float* xr = in + row * CDIM;
  float v0 = xr[tid], v1 = xr[tid + 256], v2 = xr[tid + 512];
  float mean = bred(v0 + v1 + v2, 0) * (1.0f / CDIM);
  float d0 = v0 - mean, d1 = v1 - mean, d2 = v2 - mean;
  float var = bred(d0 * d0 + d1 * d1 + d2 * d2, 0) * (1.0f / CDIM);
  float inv = 1.0f / sqrtf(var + 1e-5f);
  float* orow = out + row * CDIM;
  orow[tid]       = d0 * inv * w[tid]       + b[tid];
  orow[tid + 256] = d1 * inv * w[tid + 256] + b[tid + 256];
  orow[tid + 512] = d2 * inv * w[tid + 512] + b[tid + 512];
}

// ---------- layernorm, split bf16 hi/lo out (new path) ----------
__global__ void k_layernorm_sp(const float* __restrict__ in, const float* __restrict__ w,
                               const float* __restrict__ b, u16* __restrict__ ohi,
                               u16* __restrict__ olo) {
  const long row = blockIdx.x;
  const int tid = threadIdx.x;
  const float* xr = in + row * CDIM;
  float v0 = xr[tid], v1 = xr[tid + 256], v2 = xr[tid + 512];
  float mean = bred(v0 + v1 + v2, 0) * (1.0f / CDIM);
  float d0 = v0 - mean, d1 = v1 - mean, d2 = v2 - mean;
  float var = bred(d0 * d0 + d1 * d1 + d2 * d2, 0) * (1.0f / CDIM);
  float inv = 1.0f / sqrtf(var + 1e-5f);
  float o0 = d0 * inv * w[tid]       + b[tid];
  float o1 = d1 * inv * w[tid + 256] + b[tid + 256];
  float o2 = d2 * inv * w[tid + 512] + b[tid + 512];
  u16* hr = ohi + row * CDIM;
  u16* lr = olo + row * CDIM;
  u16 h0 = f2bf_rne(o0), h1 = f2bf_rne(o1), h2 = f2bf_rne(o2);
  hr[tid] = h0;       lr[tid] = f2bf_rne(o0 - bf2f(h0));
  hr[tid + 256] = h1; lr[tid + 256] = f2bf_rne(o1 - bf2f(h1));
  hr[tid + 512] = h2; lr[tid + 512] = f2bf_rne(o2 - bf2f(h2));
}

// ---------- weight transpose + split: W[K][N] fp32 -> Wt_hi/lo [N][K] bf16 ----------
__global__ void k_wsplit(const float* __restrict__ W, u16* __restrict__ Whi,
                         u16* __restrict__ Wlo, int K, int N, long wstride, long ostride) {
  W += blockIdx.z * wstride;
  Whi += blockIdx.z * ostride;
  Wlo += blockIdx.z * ostride;
  const int n0 = blockIdx.x << 6, k0 = blockIdx.y << 6;
  __shared__ float t[64][65];
  const int tid = threadIdx.x;
  const int cr = tid >> 4;          // 0..15
  const int cc = (tid & 15) << 2;   // 0..60 step 4
#pragma unroll
  for (int it = 0; it < 4; ++it) {
    const int r = cr + it * 16;
    float4 v = *(const float4*)(W + (long)(k0 + r) * N + n0 + cc);
    t[r][cc] = v.x; t[r][cc + 1] = v.y; t[r][cc + 2] = v.z; t[r][cc + 3] = v.w;
  }
  __syncthreads();
#pragma unroll
  for (int it = 0; it < 4; ++it) {
    const int n = cr + it * 16;
    ushort4v hv, lv;
#pragma unroll
    for (int j = 0; j < 4; ++j) {
      float f = t[cc + j][n];
      u16 hh = f2bf_rne(f);
      hv[j] = hh;
      lv[j] = f2bf_rne(f - bf2f(hh));
    }
    *(ushort4v*)&Whi[(long)(n0 + n) * K + k0 + cc] = hv;
    *(ushort4v*)&Wlo[(long)(n0 + n) * K + k0 + cc] = lv;
  }
}

// ---------- fp32 -> bf16 hi conversion (wte for LM head) ----------
__global__ void k_cvt_hi(const float* __restrict__ A, u16* __restrict__ O, long n) {
  long i = ((long)blockIdx.x * 256 + threadIdx.x) * 8;
  if (i >= n) return;
  float4 a = *(const float4*)(A + i);
  float4 b = *(const float4*)(A + i + 4);
  ushort8v o;
  o[0] = f2bf_rne(a.x); o[1] = f2bf_rne(a.y); o[2] = f2bf_rne(a.z); o[3] = f2bf_rne(a.w);
  o[4] = f2bf_rne(b.x); o[5] = f2bf_rne(b.y); o[6] = f2bf_rne(b.z); o[7] = f2bf_rne(b.w);
  *(ushort8v*)&O[i] = o;
}

// ---------- fp32 -> bf16 hi/lo split (qkv after atomic split-K) ----------
__global__ void k_split2(const float* __restrict__ A, u16* __restrict__ Ohi,
                         u16* __restrict__ Olo, long n) {
  long i = ((long)blockIdx.x * 256 + threadIdx.x) * 4;
  if (i >= n) return;
  float4 a = *(const float4*)(A + i);
  ushort4v hv, lv;
  hv[0] = f2bf_rne(a.x); lv[0] = f2bf_rne(a.x - bf2f(hv[0]));
  hv[1] = f2bf_rne(a.y); lv[1] = f2bf_rne(a.y - bf2f(hv[1]));
  hv[2] = f2bf_rne(a.z); lv[2] = f2bf_rne(a.z - bf2f(hv[2]));
  hv[3] = f2bf_rne(a.w); lv[3] = f2bf_rne(a.w - bf2f(hv[3]));
  *(ushort4v*)&Ohi[i] = hv;
  *(ushort4v*)&Olo[i] = lv;
}

// ---------- fp32 GEMM (PV; QK^T fallback). OSPLIT=1: write bf16 hi/lo outs ----------
template <int BT, int ACT, int OSPLIT>
__global__ __launch_bounds__(256) void k_gemm(
    const float* __restrict__ A, const float* __restrict__ B,
    const float* __restrict__ bias, float* __restrict__ C,
    u16* __restrict__ Ohi, u16* __restrict__ Olo,
    int K, int lda, int ldb, int ldc,
    long sAb, long sAh, long sBb, long sBh, long sCb, long sCh,
    int Hb, float alpha, int beta) {
  const int bid = blockIdx.z;
  const int bb = bid / Hb, hh = bid - bb * Hb;
  A += bb * sAb + hh * sAh;
  B += bb * sBb + hh * sBh;
  C += bb * sCb + hh * sCh;
  if (OSPLIT) { Ohi += bb * sCb + hh * sCh; Olo += bb * sCb + hh * sCh; }
  const int m0 = blockIdx.y << 6, n0 = blockIdx.x << 6;
  __shared__ float As[16][68];
  __shared__ float Bs[16][68];
  const int tid = threadIdx.x;
  const int r0 = (tid >> 4) << 2;
  const int c0 = (tid & 15) << 2;
  const int lr = tid >> 2;
  const int lk = (tid & 3) << 2;
  const int bk = tid >> 4;
  const int bn = (tid & 15) << 2;
  float acc[4][4] = {{0.f, 0.f, 0.f, 0.f}, {0.f, 0.f, 0.f, 0.f},
                     {0.f, 0.f, 0.f, 0.f}, {0.f, 0.f, 0.f, 0.f}};
  for (int k0 = 0; k0 < K; k0 += 16) {
    float4 av = *(const float4*)(A + (long)(m0 + lr) * lda + (k0 + lk));
    As[lk][lr] = av.x; As[lk + 1][lr] = av.y; As[lk + 2][lr] = av.z; As[lk + 3][lr] = av.w;
    if (BT) {
      float4 bv = *(const float4*)(B + (long)(n0 + lr) * ldb + (k0 + lk));
      Bs[lk][lr] = bv.x; Bs[lk + 1][lr] = bv.y; Bs[lk + 2][lr] = bv.z; Bs[lk + 3][lr] = bv.w;
    } else {
      *(float4*)&Bs[bk][bn] = *(const float4*)(B + (long)(k0 + bk) * ldb + (n0 + bn));
    }
    __syncthreads();
#pragma unroll
    for (int kk = 0; kk < 16; ++kk) {
      float4 a = *(const float4*)&As[kk][r0];
      float4 bv = *(const float4*)&Bs[kk][c0];
      acc[0][0] += a.x * bv.x; acc[0][1] += a.x * bv.y; acc[0][2] += a.x * bv.z; acc[0][3] += a.x * bv.w;
      acc[1][0] += a.y * bv.x; acc[1][1] += a.y * bv.y; acc[1][2] += a.y * bv.z; acc[1][3] += a.y * bv.w;
      acc[2][0] += a.z * bv.x; acc[2][1] += a.z * bv.y; acc[2][2] += a.z * bv.z; acc[2][3] += a.z * bv.w;
      acc[3][0] += a.w * bv.x; acc[3][1] += a.w * bv.y; acc[3][2] += a.w * bv.z; acc[3][3] += a.w * bv.w;
    }
    __syncthreads();
  }
  float4 bs4 = make_float4(0.f, 0.f, 0.f, 0.f);
  if (bias) bs4 = *(const float4*)(bias + n0 + c0);
#pragma unroll
  for (int i = 0; i < 4; ++i) {
    float* cp = C + (long)(m0 + r0 + i) * ldc + (n0 + c0);
    float4 prev = make_float4(0.f, 0.f, 0.f, 0.f);
    if (beta) prev = *(const float4*)cp;
    float4 o;
    o.x = prev.x + alpha * acc[i][0] + bs4.x;
    o.y = prev.y + alpha * acc[i][1] + bs4.y;
    o.z = prev.z + alpha * acc[i][2] + bs4.z;
    o.w = prev.w + alpha * acc[i][3] + bs4.w;
    if (ACT == 1) {
      o.x = 0.5f * o.x * (1.0f + erff(o.x * 0.70710678118654752f));
      o.y = 0.5f * o.y * (1.0f + erff(o.y * 0.70710678118654752f));
      o.z = 0.5f * o.z * (1.0f + erff(o.z * 0.70710678118654752f));
      o.w = 0.5f * o.w * (1.0f + erff(o.w * 0.70710678118654752f));
    }
    if (OSPLIT) {
      ushort4v hv, lv;
      hv[0] = f2bf_rne(o.x); lv[0] = f2bf_rne(o.x - bf2f(hv[0]));
      hv[1] = f2bf_rne(o.y); lv[1] = f2bf_rne(o.y - bf2f(hv[1]));
      hv[2] = f2bf_rne(o.z); lv[2] = f2bf_rne(o.z - bf2f(hv[2]));
      hv[3] = f2bf_rne(o.w); lv[3] = f2bf_rne(o.w - bf2f(hv[3]));
      *(ushort4v*)(Ohi + (long)(m0 + r0 + i) * ldc + (n0 + c0)) = hv;
      *(ushort4v*)(Olo + (long)(m0 + r0 + i) * ldc + (n0 + c0)) = lv;
    } else {
      *(float4*)cp = o;
    }
  }
}

// ---------- pre-split bf16 MFMA GEMM (m97 staging structure) ----------
// A_hi/lo: [M][K] bf16 row-major (lda). B_hi/lo: [N][K] bf16 row-major (ldb).
// C fp32 [M][N] (ldc). TERMS=3: hi*hi + hi*lo + lo*hi. OUTMODE: 0 fp32 C;
// 1 bf16 hi/lo only; 2 both. Batched OR split-K via blockIdx.z = bb*Hb+hh
// with element strides (split-K: sAh=sBh=Ksplit, sCh=0, ATOMIC=1).
// ATOMIC=1: epilogue atomicAdd into C (bias applied by hh==0 only).
// XCD=1: bijective chunk swizzle over the x/y plane (swzq = nwg_xy/8);
// requires nwg_xy % 8 == 0. GS=1: blockIdx.x is the m dim (m fastest ->
// chunks share B panels in one XCD's L2).
template <int TERMS, int ACT, int OUTMODE, int GS, int ATOMIC, int XCD>
__global__ __launch_bounds__(256) void k_gemm_bt(
    const u16* __restrict__ Ahi, const u16* __restrict__ Alo,
    const u16* __restrict__ Bhi, const u16* __restrict__ Blo,
    const float* __restrict__ bias, float* __restrict__ C,
    u16* __restrict__ Ohi, u16* __restrict__ Olo,
    int K, int lda, int ldb, int ldc,
    long sAb, long sAh, long sBb, long sBh, long sCb, long sCh,
    int Hb, float alpha, int beta, int swzq) {
  const int bz = blockIdx.z;
  const int bb = bz / Hb, hh = bz - bb * Hb;
  Ahi += bb * sAb + hh * sAh;
  Bhi += bb * sBb + hh * sBh;
  if (TERMS > 1) {
    Alo += bb * sAb + hh * sAh;
    Blo += bb * sBb + hh * sBh;
  }
  if (OUTMODE != 1) C += bb * sCb + hh * sCh;
  if (OUTMODE >= 1) { Ohi += bb * sCb + hh * sCh; Olo += bb * sCb + hh * sCh; }
  int bx = blockIdx.x, by = blockIdx.y;
  if (XCD) {
    const int flat = by * gridDim.x + bx;
    const int wg = (flat & 7) * swzq + (flat >> 3);
    bx = wg % gridDim.x;
    by = wg / gridDim.x;
  }
  const int m0 = (GS ? bx : by) << 7;
  const int n0 = (GS ? by : bx) << 7;
  __shared__ u16 sm[(TERMS > 1 ? 4 : 2) * 4096];
  u16* sAhi = sm;
  u16* sAlo = sm + 4096;                              // used only TERMS>1
  u16* sBhi = sm + (TERMS > 1 ? 2 : 1) * 4096;
  u16* sBlo = sBhi + 4096;                            // used only TERMS>1
  const int tid = threadIdx.x;
  const int lane = tid & 63, wave = tid >> 6;
  const int wm = (wave & 1) << 6, wn = (wave >> 1) << 6;
  const int fr = lane & 15, fk = (lane >> 4) << 3;
  // staging: wave w fills chunks 2w,2w+1 (16 rows x 32 cols each);
  // lane l covers row chunkrow + (l>>2), cols (l&3)*8 .. +7  (16 B).
  const int sr = lane >> 2;
  const int sc = (lane & 3) << 3;
  const long arow = (long)(m0 + wave * 32 + sr);
  const long brow = (long)(n0 + wave * 32 + sr);
  const int lbase = wave * 1024;   // u16 index of this wave's first chunk

  floatx4 acc[4][4];
#pragma unroll
  for (int i = 0; i < 4; ++i)
#pragma unroll
    for (int j = 0; j < 4; ++j) acc[i][j] = (floatx4)(0.0f);

  for (int k0 = 0; k0 < K; k0 += 32) {
    {
      const u16* ga = Ahi + arow * lda + k0 + sc;
      const u16* gb = Bhi + brow * ldb + k0 + sc;
      gload16(ga, &sAhi[lbase]);
      gload16(ga + (long)16 * lda, &sAhi[lbase + 512]);
      gload16(gb, &sBhi[lbase]);
      gload16(gb + (long)16 * ldb, &sBhi[lbase + 512]);
      if (TERMS > 1) {
        const u16* ga2 = Alo + arow * lda + k0 + sc;
        const u16* gb2 = Blo + brow * ldb + k0 + sc;
        gload16(ga2, &sAlo[lbase]);
        gload16(ga2 + (long)16 * lda, &sAlo[lbase + 512]);
        gload16(gb2, &sBlo[lbase]);
        gload16(gb2 + (long)16 * ldb, &sBlo[lbase + 512]);
      }
    }
    __syncthreads();
    short8 ah[4], bh[4], al[4], bl[4];
#pragma unroll
    for (int i = 0; i < 4; ++i) {
      ah[i] = *(const short8*)&sAhi[(wm + i * 16 + fr) * 32 + fk];
      bh[i] = *(const short8*)&sBhi[(wn + i * 16 + fr) * 32 + fk];
      if (TERMS > 1) {
        al[i] = *(const short8*)&sAlo[(wm + i * 16 + fr) * 32 + fk];
        bl[i] = *(const short8*)&sBlo[(wn + i * 16 + fr) * 32 + fk];
      }
    }
#pragma unroll
    for (int i = 0; i < 4; ++i)
#pragma unroll
      for (int j = 0; j < 4; ++j) {
        acc[i][j] = __builtin_amdgcn_mfma_f32_16x16x32_bf16(ah[i], bh[j], acc[i][j], 0, 0, 0);
        if (TERMS > 1) {
          acc[i][j] = __builtin_amdgcn_mfma_f32_16x16x32_bf16(ah[i], bl[j], acc[i][j], 0, 0, 0);
          acc[i][j] = __builtin_amdgcn_mfma_f32_16x16x32_bf16(al[i], bh[j], acc[i][j], 0, 0, 0);
        }
      }
    __syncthreads();
  }
  // epilogue: C/D map col=lane&15, row=(lane>>4)*4+reg
  const int er = (lane >> 4) << 2, ec = lane & 15;
#pragma unroll
  for (int j = 0; j < 4; ++j) {
    const int col = n0 + wn + j * 16 + ec;
    const float bsv = (bias && (!ATOMIC || hh == 0)) ? bias[col] : 0.0f;
#pragma unroll
    for (int i = 0; i < 4; ++i) {
      const long rbase = (long)(m0 + wm + i * 16 + er);
#pragma unroll
      for (int r = 0; r < 4; ++r) {
        const long off = (rbase + r) * ldc + col;
        float o = alpha * acc[i][j][r] + bsv;
        if (ATOMIC) {
          atomicAdd(&C[off], o);
        } else {
          if (beta) o += C[off];
          if (ACT == 1) o = 0.5f * o * (1.0f + erff(o * 0.70710678118654752f));
          if (OUTMODE != 1) C[off] = o;
          if (OUTMODE >= 1) {
            u16 hv = f2bf_rne(o);
            Ohi[off] = hv;
            Olo[off] = f2bf_rne(o - bf2f(hv));
          }
        }
      }
    }
  }
}

// ---------- OLD: MFMA GEMM with in-loop conversion (fallback path) ----------
template <int BT, int TERMS, int ACT, int GS>
__global__ __launch_bounds__(256) void k_gemm_mfma(
    const float* __restrict__ A, const float* __restrict__ B,
    const float* __restrict__ bias, float* __restrict__ C,
    int K, int lda, int ldb, int ldc, int beta) {
  const int m0 = (GS ? blockIdx.x : blockIdx.y) << 7;
  const int n0 = (GS ? blockIdx.y : blockIdx.x) << 7;
  __shared__ unsigned short sm[(TERMS > 1 ? 4 : 2) * 128 * LDSK];
  unsigned short* As_hi = sm;
  unsigned short* As_lo = (TERMS > 1) ? (sm + 128 * LDSK) : sm;
  unsigned short* Bs_hi = sm + (TERMS > 1 ? 2 : 1) * 128 * LDSK;
  unsigned short* Bs_lo = (TERMS > 1) ? (Bs_hi + 128 * LDSK) : Bs_hi;
  const int tid = threadIdx.x;
  const int lane = tid & 63, wave = tid >> 6;
  const int wm = (wave & 1) << 6, wn = (wave >> 1) << 6;
  const int fr = lane & 15;
  const int fk = (lane >> 4) << 3;
  const int ar = tid >> 1, ak = (tid & 1) << 4;
  const int bn = tid & 31, bk = (tid >> 5) << 2;

  floatx4 acc[4][4];
#pragma unroll
  for (int i = 0; i < 4; ++i)
#pragma unroll
    for (int j = 0; j < 4; ++j) acc[i][j] = (floatx4)(0.0f);

  for (int k0 = 0; k0 < K; k0 += 32) {
    {
      const float* ap = A + (long)(m0 + ar) * lda + (k0 + ak);
      float4 f0 = *(const float4*)(ap);
      float4 f1 = *(const float4*)(ap + 4);
      float4 f2 = *(const float4*)(ap + 8);
      float4 f3 = *(const float4*)(ap + 12);
      float va[16] = {f0.x, f0.y, f0.z, f0.w, f1.x, f1.y, f1.z, f1.w,
                      f2.x, f2.y, f2.z, f2.w, f3.x, f3.y, f3.z, f3.w};
      ushort8v h0, h1, l0, l1;
#pragma unroll
      for (int i = 0; i < 8; ++i) {
        unsigned short hA = f2bf_rne(va[i]);
        unsigned short hB = f2bf_rne(va[8 + i]);
        h0[i] = hA; h1[i] = hB;
        if (TERMS > 1) {
          l0[i] = f2bf_rne(va[i] - bf2f(hA));
          l1[i] = f2bf_rne(va[8 + i] - bf2f(hB));
        }
      }
      *(ushort8v*)&As_hi[ar * LDSK + ak]     = h0;
      *(ushort8v*)&As_hi[ar * LDSK + ak + 8] = h1;
      if (TERMS > 1) {
        *(ushort8v*)&As_lo[ar * LDSK + ak]     = l0;
        *(ushort8v*)&As_lo[ar * LDSK + ak + 8] = l1;
      }
    }
    if (BT) {
      const float* bp = B + (long)(n0 + ar) * ldb + (k0 + ak);
      float4 f0 = *(const float4*)(bp);
      float4 f1 = *(const float4*)(bp + 4);
      float4 f2 = *(const float4*)(bp + 8);
      float4 f3 = *(const float4*)(bp + 12);
      float vb[16] = {f0.x, f0.y, f0.z, f0.w, f1.x, f1.y, f1.z, f1.w,
                      f2.x, f2.y, f2.z, f2.w, f3.x, f3.y, f3.z, f3.w};
      ushort8v h0, h1, l0, l1;
#pragma unroll
      for (int i = 0; i < 8; ++i) {
        unsigned short hA = f2bf_rne(vb[i]);
        unsigned short hB = f2bf_rne(vb[8 + i]);
        h0[i] = hA; h1[i] = hB;
        if (TERMS > 1) {
          l0[i] = f2bf_rne(vb[i] - bf2f(hA));
          l1[i] = f2bf_rne(vb[8 + i] - bf2f(hB));
        }
      }
      *(ushort8v*)&Bs_hi[ar * LDSK + ak]     = h0;
      *(ushort8v*)&Bs_hi[ar * LDSK + ak + 8] = h1;
      if (TERMS > 1) {
        *(ushort8v*)&Bs_lo[ar * LDSK + ak]     = l0;
        *(ushort8v*)&Bs_lo[ar * LDSK + ak + 8] = l1;
      }
    } else {
      float bvv[4][4];
#pragma unroll
      for (int j = 0; j < 4; ++j)
#pragma unroll
        for (int r = 0; r < 4; ++r)
          bvv[j][r] = B[(long)(k0 + bk + r) * ldb + (n0 + bn + 32 * j)];
#pragma unroll
      for (int j = 0; j < 4; ++j) {
        ushort4v hv, lv;
#pragma unroll
        for (int r = 0; r < 4; ++r) {
          unsigned short hh = f2bf_rne(bvv[j][r]);
          hv[r] = hh;
          if (TERMS > 1) lv[r] = f2bf_rne(bvv[j][r] - bf2f(hh));
        }
        *(ushort4v*)&Bs_hi[(bn + 32 * j) * LDSK + bk] = hv;
        if (TERMS > 1) *(ushort4v*)&Bs_lo[(bn + 32 * j) * LDSK + bk] = lv;
      }
    }
    __syncthreads();
    short8 a_hi[4], a_lo[4], b_hi[4], b_lo[4];
#pragma unroll
    for (int i = 0; i < 4; ++i) {
      a_hi[i] = *(const short8*)&As_hi[(wm + i * 16 + fr) * LDSK + fk];
      b_hi[i] = *(const short8*)&Bs_hi[(wn + i * 16 + fr) * LDSK + fk];
      if (TERMS > 1) {
        a_lo[i] = *(const short8*)&As_lo[(wm + i * 16 + fr) * LDSK + fk];
        b_lo[i] = *(const short8*)&Bs_lo[(wn + i * 16 + fr) * LDSK + fk];
      }
    }
#pragma unroll
    for (int i = 0; i < 4; ++i)
#pragma unroll
      for (int j = 0; j < 4; ++j) {
        acc[i][j] = __builtin_amdgcn_mfma_f32_16x16x32_bf16(a_hi[i], b_hi[j], acc[i][j], 0, 0, 0);
        if (TERMS > 1) {
          acc[i][j] = __builtin_amdgcn_mfma_f32_16x16x32_bf16(a_hi[i], b_lo[j], acc[i][j], 0, 0, 0);
          acc[i][j] = __builtin_amdgcn_mfma_f32_16x16x32_bf16(a_lo[i], b_hi[j], acc[i][j], 0, 0, 0);
        }
      }
    __syncthreads();
  }
  const int er = (lane >> 4) << 2;
  const int ec = lane & 15;
#pragma unroll
  for (int j = 0; j < 4; ++j) {
    const int col = n0 + wn + j * 16 + ec;
    const float bsv = bias ? bias[col] : 0.0f;
#pragma unroll
    for (int i = 0; i < 4; ++i) {
#pragma unroll
      for (int r = 0; r < 4; ++r) {
        float* cp = C + (long)(m0 + wm + i * 16 + er + r) * ldc + col;
        float o = acc[i][j][r] + bsv + (beta ? *cp : 0.0f);
        if (ACT == 1) o = 0.5f * o * (1.0f + erff(o * 0.70710678118654752f));
        *cp = o;
      }
    }
  }
}

// ---------- masked softmax over keys ----------
__global__ void k_softmax(float* __restrict__ att, const float* __restrict__ am) {
  const int q = blockIdx.x;
  const int bh = blockIdx.y;
  const int b = bh / HNUM;
  float* row = att + ((long)bh * TDIM + q) * TDIM;
  const float* amr = am + b * TDIM;
  const int tid = threadIdx.x;
  float lv[4];
  bool valid[4];
  float mx = -INFINITY;
#pragma unroll
  for (int i = 0; i < 4; ++i) {
    const int k = tid + (i << 8);
    const bool ok = (k <= q) && (amr[k] > 0.0f);
    valid[i] = ok;
    lv[i] = ok ? row[k] : -INFINITY;
    mx = fmaxf(mx, lv[i]);
  }
  mx = bred(mx, 1);
  float sum = 0.f;
#pragma unroll
  for (int i = 0; i < 4; ++i) {
    lv[i] = valid[i] ? expf(lv[i] - mx) : 0.0f;
    sum += lv[i];
  }
  sum = bred(sum, 0);
  const float inv = sum > 0.f ? 1.0f / sum : 0.0f;
#pragma unroll
  for (int i = 0; i < 4; ++i) row[tid + (i << 8)] = lv[i] * inv;
}

// ---------- imp[b,k] partial column sums of att ----------
__global__ void k_impsum(const float* __restrict__ att, float* __restrict__ imp) {
  const int h = blockIdx.x >> 2, qc = blockIdx.x & 3;
  const int b = blockIdx.z;
  const int k = (blockIdx.y << 8) + threadIdx.x;
  const float* base = att + (((long)(b * HNUM + h) * TDIM) + (qc << 8)) * TDIM + k;
  float s = 0.f;
#pragma unroll 4
  for (int q = 0; q < 256; ++q) s += base[(long)q * TDIM];
  atomicAdd(&imp[b * TDIM + k], s);
}

// ---------- threshold mask ----------
__global__ void k_mask(const float* __restrict__ imp, const float* __restrict__ thp,
                       float* __restrict__ am, float* __restrict__ x) {
  const int row = blockIdx.x;
  const int t = row & (TDIM - 1);
  const float impv = imp[row] * (1.0f / (HNUM * TDIM));
  float pm = (impv >= *thp) ? 1.0f : 0.0f;
  if (t >= TDIM - 64) pm = 1.0f;
  const float cm = am[row] * pm;
  float* xr = x + (long)row * CDIM;
  const int tid = threadIdx.x;
  xr[tid] *= cm;
  xr[tid + 256] *= cm;
  xr[tid + 512] *= cm;
  if (tid == 0) am[row] = cm;
}

// ---------- loss (single-pass online softmax) ----------
__global__ void k_lossrow(const float* __restrict__ logits, const int* __restrict__ tgt,
                          float* __restrict__ nll) {
  const int row = blockIdx.x;
  const float* lr = logits + (long)row * VDIM;
  const int tid = threadIdx.x;
  float mx = -INFINITY, s = 0.f;
  for (int k = tid * 4; k < VDIM; k += 1024) {
    float4 v = *(const float4*)(lr + k);
    float m4 = fmaxf(fmaxf(v.x, v.y), fmaxf(v.z, v.w));
    if (m4 > mx) { s *= expf(mx - m4); mx = m4; }
    s += expf(v.x - mx) + expf(v.y - mx) + expf(v.z - mx) + expf(v.w - mx);
  }
  __shared__ float sm_[256], ss_[256];
  sm_[tid] = mx; ss_[tid] = s;
  __syncthreads();
#pragma unroll
  for (int st = 128; st > 0; st >>= 1) {
    if (tid < st) {
      float m2 = sm_[tid + st], s2 = ss_[tid + st];
      float M = fmaxf(sm_[tid], m2);
      ss_[tid] = ss_[tid] * expf(sm_[tid] - M) + s2 * expf(m2 - M);
      sm_[tid] = M;
    }
    __syncthreads();
  }
  if (tid == 0) {
    const int t = tgt[row];
    nll[row] = (t != -1) ? -(lr[t] - sm_[0] - logf(ss_[0])) : 0.0f;
  }
}

__global__ void k_lossfinal(const float* __restrict__ nll, const int* __restrict__ tgt,
                            float* __restrict__ out) {
  const int tid = threadIdx.x;
  float s = 0.f, cnt = 0.f;
  for (int r = tid; r < NROWS; r += 256) {
    s += nll[r];
    cnt += (tgt[r] != -1) ? 1.f : 0.f;
  }
  s = bred(s, 0);
  cnt = bred(cnt, 0);
  if (tid == 0) out[0] = s / cnt;
}

extern "C" void kernel_launch(void* const* d_in, const int* in_sizes, int n_in,
                              void* d_out, int out_size, void* d_ws, size_t ws_size,
                              hipStream_t stream) {
  (void)in_sizes; (void)n_in; (void)out_size;
  const int* idx      = (const int*)d_in[0];
  const int* targets  = (const int*)d_in[1];
  const float* wte    = (const float*)d_in[2];
  const float* wpe    = (const float*)d_in[3];
  const float* ln1_w  = (const float*)d_in[4];
  const float* ln1_b  = (const float*)d_in[5];
  const float* attn_w = (const float*)d_in[6];
  const float* attn_b = (const float*)d_in[7];
  const float* proj_w = (const float*)d_in[8];
  const float* proj_b = (const float*)d_in[9];
  const float* ln2_w  = (const float*)d_in[10];
  const float* ln2_b  = (const float*)d_in[11];
  const float* fc_w   = (const float*)d_in[12];
  const float* fc_b   = (const float*)d_in[13];
  const float* mlp_w  = (const float*)d_in[14];
  const float* mlp_b  = (const float*)d_in[15];
  const float* thres  = (const float*)d_in[16];
  const float* lnf_w  = (const float*)d_in[17];
  const float* lnf_b  = (const float*)d_in[18];
  float* logits = (float*)d_out;
  float* loss = logits + (long)NROWS * VDIM;

  const long F_X   = (long)NROWS * CDIM;
  const long F_QKV = (long)NROWS * 3 * CDIM;
  const long F_ATT = (long)BDIM * HNUM * TDIM * TDIM;
  const long U_H   = (long)NROWS * CDIM;
  const long U_ACT = (long)NROWS * 4 * CDIM;
  const long U_QKV = F_QKV;
  const long WA = (long)CDIM * 3 * CDIM;   // per-layer weight elem counts
  const long WP = (long)CDIM * CDIM;
  const long WF = (long)CDIM * 4 * CDIM;
  const long WM = (long)4 * CDIM * CDIM;
  const long WPL = WA + WP + WF + WM;      // 7,077,888
  const long U_W   = (long)LNUM * WPL;
  const long U_WTE = (long)VDIM * CDIM;
  const unsigned long long need =
      4ull * (F_X + F_QKV + F_ATT + 3 * NROWS) +
      2ull * (4 * U_H + 2 * U_ACT + 2 * U_QKV + 2 * U_W + U_WTE);

  // common float region
  float* x   = (float*)d_ws;
  float* qkv = x + F_X;

  if (ws_size >= need) {
    // ================= NEW PATH: pre-split bf16 operands =================
    float* att = qkv + F_QKV;
    float* am  = att + F_ATT;
    float* imp = am + NROWS;
    float* nll = imp + NROWS;
    u16* h_hi   = (u16*)(nll + NROWS);
    u16* h_lo   = h_hi + U_H;
    u16* y_hi   = h_lo + U_H;
    u16* y_lo   = y_hi + U_H;
    u16* act_hi = y_lo + U_H;
    u16* act_lo = act_hi + U_ACT;
    u16* qkv_hi = act_lo + U_ACT;
    u16* qkv_lo = qkv_hi + U_QKV;
    u16* w_hi   = qkv_lo + U_QKV;
    u16* w_lo   = w_hi + U_W;
    u16* wte_h  = w_lo + U_W;

    // --- pre-pass: weight transpose+split (K x N fp32 -> N x K bf16 hi/lo) ---
    k_wsplit<<<dim3(3 * CDIM / 64, CDIM / 64, LNUM), 256, 0, stream>>>(
        attn_w, w_hi, w_lo, CDIM, 3 * CDIM, WA, WPL);
    k_wsplit<<<dim3(CDIM / 64, CDIM / 64, LNUM), 256, 0, stream>>>(
        proj_w, w_hi + WA, w_lo + WA, CDIM, CDIM, WP, WPL);
    k_wsplit<<<dim3(4 * CDIM / 64, CDIM / 64, LNUM), 256, 0, stream>>>(
        fc_w, w_hi + WA + WP, w_lo + WA + WP, CDIM, 4 * CDIM, WF, WPL);
    k_wsplit<<<dim3(CDIM / 64, 4 * CDIM / 64, LNUM), 256, 0, stream>>>(
        mlp_w, w_hi + WA + WP + WF, w_lo + WA + WP + WF, 4 * CDIM, CDIM, WM, WPL);
    k_cvt_hi<<<(unsigned)((U_WTE / 8 + 255) / 256), 256, 0, stream>>>(wte, wte_h, U_WTE);

    k_embed<<<NROWS, 256, 0, stream>>>(idx, wte, wpe, x, am);

    for (int l = 0; l < LNUM; ++l) {
      const u16* wa_h = w_hi + (long)l * WPL;
      const u16* wa_l = w_lo + (long)l * WPL;
      const u16* wp_h = wa_h + WA;
      const u16* wp_l = wa_l + WA;
      const u16* wf_h = wp_h + WP;
      const u16* wf_l = wp_l + WP;
      const u16* wm_h = wf_h + WF;
      const u16* wm_l = wf_l + WF;

      k_layernorm_sp<<<NROWS, 256, 0, stream>>>(x, ln1_w + l * CDIM, ln1_b + l * CDIM, h_hi, h_lo);
      // qkv = h @ attn_w + b: split-K=2 atomic into zeroed fp32, then split
      hipMemsetAsync(qkv, 0, F_QKV * sizeof(float), stream);
      k_gemm_bt<3, 0, 0, 1, 1, 1><<<dim3(16, 18, 2), 256, 0, stream>>>(
          h_hi, h_lo, wa_h, wa_l, attn_b + (long)l * 3 * CDIM, qkv, nullptr, nullptr,
          384, 768, 768, 2304, 0, 384, 0, 384, 0, 0, 2, 1.0f, 0, 36);
      k_split2<<<(unsigned)(F_QKV / 4 / 256), 256, 0, stream>>>(qkv, qkv_hi, qkv_lo, F_QKV);
      // scores = q @ k^T / 8 (batched 3-term split-bf16 MFMA, K=64)
      k_gemm_bt<3, 0, 0, 0, 0, 0><<<dim3(8, 8, BDIM * HNUM), 256, 0, stream>>>(
          qkv_hi, qkv_lo, qkv_hi + CDIM, qkv_lo + CDIM, nullptr, att, nullptr, nullptr,
          64, 2304, 2304, 1024,
          (long)TDIM * 3 * CDIM, 64, (long)TDIM * 3 * CDIM, 64,
          (long)HNUM * TDIM * TDIM, (long)TDIM * TDIM, HNUM, 0.125f, 0, 0);
      k_softmax<<<dim3(TDIM, BDIM * HNUM), 256, 0, stream>>>(att, am);
      hipMemsetAsync(imp, 0, NROWS * sizeof(float), stream);
      k_impsum<<<dim3(HNUM * 4, 4, BDIM), 256, 0, stream>>>(att, imp);
      // y = att @ v (fp32), epilogue emits y hi/lo split
      k_gemm<0, 0, 1><<<dim3(1, 16, BDIM * HNUM), 256, 0, stream>>>(
          att, qkv + 2 * CDIM, nullptr, nullptr, y_hi, y_lo,
          1024, 1024, 2304, 768,
          (long)HNUM * TDIM * TDIM, (long)TDIM * TDIM, (long)TDIM * 3 * CDIM, 64,
          (long)TDIM * CDIM, 64, HNUM, 1.0f, 0);
      // x += y @ proj_w + b: split-K=4 atomic into x (residual already there)
      k_gemm_bt<3, 0, 0, 1, 1, 1><<<dim3(16, 6, 4), 256, 0, stream>>>(
          y_hi, y_lo, wp_h, wp_l, proj_b + (long)l * CDIM, x, nullptr, nullptr,
          192, 768, 768, 768, 0, 192, 0, 192, 0, 0, 4, 1.0f, 0, 12);
      k_mask<<<NROWS, 256, 0, stream>>>(imp, thres + l, am, x);
      k_layernorm_sp<<<NROWS, 256, 0, stream>>>(x, ln2_w + l * CDIM, ln2_b + l * CDIM, h_hi, h_lo);
      // act = gelu(h @ fc_w + b), emitted as hi/lo split only
      k_gemm_bt<3, 1, 1, 1, 0, 1><<<dim3(16, 24), 256, 0, stream>>>(
          h_hi, h_lo, wf_h, wf_l, fc_b + (long)l * 4 * CDIM, nullptr, act_hi, act_lo,
          768, 768, 768, 3072, 0, 0, 0, 0, 0, 0, 1, 1.0f, 0, 48);
      // x += act @ mlp_w + b: split-K=4 atomic into x
      k_gemm_bt<3, 0, 0, 1, 1, 1><<<dim3(16, 6, 4), 256, 0, stream>>>(
          act_hi, act_lo, wm_h, wm_l, mlp_b + (long)l * CDIM, x, nullptr, nullptr,
          768, 3072, 3072, 768, 0, 768, 0, 768, 0, 0, 4, 1.0f, 0, 12);
    }

    k_layernorm_sp<<<NROWS, 256, 0, stream>>>(x, lnf_w, lnf_b, h_hi, h_lo);
    // logits = h @ wte^T (plain bf16, pre-converted wte; m-fastest grid +
    // XCD chunk swizzle: each XCD owns ~49 contiguous wte n-tiles)
    k_gemm_bt<1, 0, 0, 1, 0, 1><<<dim3(16, 393), 256, 0, stream>>>(
        h_hi, nullptr, wte_h, nullptr, nullptr, logits, nullptr, nullptr,
        768, 768, 768, VDIM, 0, 0, 0, 0, 0, 0, 1, 1.0f, 0, 786);
    k_lossrow<<<NROWS, 256, 0, stream>>>(logits, targets, nll);
    k_lossfinal<<<1, 256, 0, stream>>>(nll, targets, loss);
  } else {
    // ================= FALLBACK: round-0 verified path =================
    float* h    = x + F_X;
    float* qkv2 = h + F_X;
    float* att  = qkv2 + F_QKV;
    float* ybuf = att + F_ATT;
    float* act  = ybuf + F_X;
    float* am   = act + (long)NROWS * 4 * CDIM;
    float* imp  = am + NROWS;
    float* nll  = imp + NROWS;

    k_embed<<<NROWS, 256, 0, stream>>>(idx, wte, wpe, x, am);
    for (int l = 0; l < LNUM; ++l) {
      k_layernorm<<<NROWS, 256, 0, stream>>>(x, ln1_w + l * CDIM, ln1_b + l * CDIM, h);
      k_gemm_mfma<0, 3, 0, 0><<<dim3(18, 16), 256, 0, stream>>>(
          h, attn_w + (long)l * CDIM * 3 * CDIM, attn_b + (long)l * 3 * CDIM, qkv2,
          768, 768, 2304, 2304, 0);
      k_gemm<1, 0, 0><<<dim3(16, 16, 24), 256, 0, stream>>>(
          qkv2, qkv2 + CDIM, nullptr, att, nullptr, nullptr,
          64, 2304, 2304, 1024,
          (long)TDIM * 3 * CDIM, 64, (long)TDIM * 3 * CDIM, 64,
          (long)HNUM * TDIM * TDIM, (long)TDIM * TDIM, HNUM, 0.125f, 0);
      k_softmax<<<dim3(TDIM, BDIM * HNUM), 256, 0, stream>>>(att, am);
      hipMemsetAsync(imp, 0, NROWS * sizeof(float), stream);
      k_impsum<<<dim3(HNUM * 4, 4, BDIM), 256, 0, stream>>>(att, imp);
      k_gemm<0, 0, 0><<<dim3(1, 16, 24), 256, 0, stream>>>(
          att, qkv2 + 2 * CDIM, nullptr, ybuf, nullptr, nullptr,
          1024, 1024, 2304, 768,
          (long)HNUM * TDIM * TDIM, (long)TDIM * TDIM, (long)TDIM * 3 * CDIM, 64,
          (long)TDIM * CDIM, 64, HNUM, 1.0f, 0);
      k_gemm_mfma<0, 3, 0, 0><<<dim3(6, 16), 256, 0, stream>>>(
          ybuf, proj_w + (long)l * CDIM * CDIM, proj_b + (long)l * CDIM, x,
          768, 768, 768, 768, 1);
      k_mask<<<NROWS, 256, 0, stream>>>(imp, thres + l, am, x);
      k_layernorm<<<NROWS, 256, 0, stream>>>(x, ln2_w + l * CDIM, ln2_b + l * CDIM, h);
      k_gemm_mfma<0, 3, 1, 0><<<dim3(24, 16), 256, 0, stream>>>(
          h, fc_w + (long)l * CDIM * 4 * CDIM, fc_b + (long)l * 4 * CDIM, act,
          768, 768, 3072, 3072, 0);
      k_gemm_mfma<0, 3, 0, 0><<<dim3(6, 16), 256, 0, stream>>>(
          act, mlp_w + (long)l * 4 * CDIM * CDIM, mlp_b + (long)l * CDIM, x,
          3072, 3072, 768, 768, 1);
    }
    k_layernorm<<<NROWS, 256, 0, stream>>>(x, lnf_w, lnf_b, h);
    k_gemm_mfma<1, 1, 0, 1><<<dim3(16, 393), 256, 0, stream>>>(
        h, wte, nullptr, logits, 768, 768, 768, VDIM, 0);
    k_lossrow<<<NROWS, 256, 0, stream>>>(logits, targets, nll);
    k_lossfinal<<<1, 256, 0, stream>>>(nll, targets, loss);
  }
}